// Round 7
// baseline (155.828 us; speedup 1.0000x reference)
//
#include <hip/hip_runtime.h>

#define BB 16
#define CC 256
#define NN 4096
#define CN (CC*NN)
#define GG 8
#define EPSF 1e-8f
#define NT 64      // n-tile per route block
#define STR 68     // padded LDS row stride (words); 68*4=272 B, 16B-aligned rows
#define PSTR 65    // pool stride (odd -> conflict-free b32)

// ---------------- conv(1x1)+relu+pool partials ----------------------------------------------
// grid: 16 b x 32 n-chunks(128) x 2 d-halves. block: 256 thr = 4 waves (dq: 8 d each).
// Explicit 8-deep double-buffered float2 prefetch (named bufs, static indexing).
// Weights: 32KB LDS, transposed in from conv_w directly; read wave-uniform.
__global__ __launch_bounds__(256) void k_conv(const float* __restrict__ x,
                                              const float* __restrict__ conv_w,
                                              const float* __restrict__ conv_b,
                                              float* __restrict__ pooledpart) {
  const int dh = blockIdx.x & 1;
  const int chunk = (blockIdx.x >> 1) & 31;
  const int b = blockIdx.x >> 6;
  const int t = threadIdx.x;
  const int lane = t & 63;
  const int wv = t >> 6;  // dq
  const int d0 = dh * 32 + wv * 8;
  __shared__ float wls[256 * 32];  // wls[c][j] = conv_w[dh*32+j][c]
#pragma unroll
  for (int k = 0; k < 32; ++k) {
    int idx = k * 256 + t;
    int j = idx >> 8, c = idx & 255;
    wls[c * 32 + j] = conv_w[(size_t)(dh * 32 + j) * 256 + c];
  }
  __syncthreads();
  const float2* xp2 = (const float2*)(x + (size_t)b * CN + chunk * 128 + lane * 2);
  const size_t cstr = NN / 2;  // float2 stride per c
  float acc[8][2];
#pragma unroll
  for (int i = 0; i < 8; ++i) { acc[i][0] = 0.f; acc[i][1] = 0.f; }
  float2 bufA[8], bufB[8];
#pragma unroll
  for (int i = 0; i < 8; ++i) bufA[i] = xp2[(size_t)i * cstr];

#define CONV_COMPUTE(BUF, GRP)                                        \
  {                                                                   \
    _Pragma("unroll") for (int i = 0; i < 8; ++i) {                   \
      const int c = (GRP) * 8 + i;                                    \
      const float* wc = &wls[c * 32 + wv * 8];                        \
      float2 xv = BUF[i];                                             \
      _Pragma("unroll") for (int dd = 0; dd < 8; ++dd) {              \
        float w = wc[dd];                                             \
        acc[dd][0] = fmaf(w, xv.x, acc[dd][0]);                       \
        acc[dd][1] = fmaf(w, xv.y, acc[dd][1]);                       \
      }                                                               \
    }                                                                 \
  }
#define CONV_LOAD(BUF, GRP)                                           \
  {                                                                   \
    const int gg = (GRP) < 32 ? (GRP) : 31;                           \
    _Pragma("unroll") for (int i = 0; i < 8; ++i)                     \
        BUF[i] = xp2[(size_t)(gg * 8 + i) * cstr];                    \
  }

  for (int grp = 0; grp < 32; grp += 2) {
    CONV_LOAD(bufB, grp + 1);
    CONV_COMPUTE(bufA, grp);
    CONV_LOAD(bufA, grp + 2);
    CONV_COMPUTE(bufB, grp + 1);
  }
#undef CONV_COMPUTE
#undef CONV_LOAD

  const float* cb = conv_b + d0;
#pragma unroll
  for (int i = 0; i < 8; ++i) {
    float bi = cb[i];
    float h = fmaxf(acc[i][0] + bi, 0.f) + fmaxf(acc[i][1] + bi, 0.f);
#pragma unroll
    for (int off = 1; off < 64; off <<= 1) h += __shfl_xor(h, off, 64);
    acc[i][0] = h;
  }
  if (lane == 0) {
    float* pp = pooledpart + ((size_t)b * 32 + chunk) * 64 + d0;
#pragma unroll
    for (int i = 0; i < 8; ++i) pp[i] = acc[i][0];
  }
}

// ---------------- pooled-reduce + logits + log(ga) + softmax -> wg --------------------------
__global__ __launch_bounds__(256) void k_logits(const float* __restrict__ pooledpart,
                                                const float* __restrict__ lin_w,
                                                const float* __restrict__ lin_b,
                                                const float* __restrict__ ga,
                                                float* __restrict__ logits,
                                                float* __restrict__ wg) {
  const int b = blockIdx.x, t = threadIdx.x;
  __shared__ float ps[64];
  if (t < 64) {
    float s = 0.f;
#pragma unroll
    for (int k = 0; k < 32; ++k) s += pooledpart[((size_t)b * 32 + k) * 64 + t];
    ps[t] = s * (1.f / 4096.f);
  }
  __syncthreads();
  const int c = t;
  float out[8];
#pragma unroll
  for (int g = 0; g < 8; ++g) {
    const float4* wr = (const float4*)(lin_w + ((size_t)c * 8 + g) * 64);
    float s = 0.f;
#pragma unroll
    for (int k4 = 0; k4 < 16; ++k4) {
      float4 wv = wr[k4];
      s += wv.x * ps[k4 * 4] + wv.y * ps[k4 * 4 + 1] + wv.z * ps[k4 * 4 + 2] +
           wv.w * ps[k4 * 4 + 3];
    }
    out[g] = s + lin_b[c * 8 + g] + logf(ga[((size_t)b * 256 + c) * 8 + g] + EPSF);
  }
  float* lp = logits + ((size_t)b * 256 + c) * 8;
  *(float4*)lp = make_float4(out[0], out[1], out[2], out[3]);
  *(float4*)(lp + 4) = make_float4(out[4], out[5], out[6], out[7]);
  float m = out[0];
#pragma unroll
  for (int g = 1; g < 8; ++g) m = fmaxf(m, out[g]);
  float sum = 0.f;
#pragma unroll
  for (int g = 0; g < 8; ++g) { out[g] = __expf(out[g] - m); sum += out[g]; }
  float r = 1.f / sum;
  float4* op = (float4*)(wg + ((size_t)b * 256 + c) * 8);
  op[0] = make_float4(out[0] * r, out[1] * r, out[2] * r, out[3] * r);
  op[1] = make_float4(out[4] * r, out[5] * r, out[6] * r, out[7] * r);
}

// ---------------- fused routing iteration: s-tile + sim partials (x staged once) ------------
// grid: 16 b x 64 n-tiles(64). block 256. LDS ~80.1KB -> 2 blocks/CU.
// w read straight from global (wave-uniform -> s_load, L2-resident).
template <int WRITE_X>
__global__ __launch_bounds__(256, 2) void k_route(const float* __restrict__ x,
                                                  const float* __restrict__ wg,
                                                  float* __restrict__ xout,
                                                  float* __restrict__ xnp,
                                                  float* __restrict__ spart2,
                                                  float* __restrict__ simpart) {
  const int b = blockIdx.x >> 6;
  const int chunk = blockIdx.x & 63;
  const int t = threadIdx.x;
  const int lane = t & 63, wv = t >> 6;
  __shared__ float xs[256 * STR];      // 69632 B (reused as pool2 in merge)
  __shared__ float st[8 * STR];        // 2176 B   s tile
  __shared__ float pool[32 * PSTR];    // 8320 B   phase-1 per-wave partials

  // stage x tile: f = k*256+t -> row r=f>>4 (c), float4-col j=f&15
  const float* xb = x + (size_t)b * CN + chunk * NT;
  float sq[16];
#pragma unroll
  for (int k = 0; k < 16; ++k) {
    int f = k * 256 + t;
    int r = f >> 4, j = f & 15;
    float4 v = *(const float4*)(xb + (size_t)r * NN + j * 4);
    *(float4*)&xs[r * STR + j * 4] = v;
    if (WRITE_X) {
      *(float4*)(xout + (size_t)b * CN + (size_t)r * NN + chunk * NT + j * 4) = v;
      sq[k] = v.x * v.x + v.y * v.y + v.z * v.z + v.w * v.w;
    }
  }
  if (WRITE_X) {
#pragma unroll
    for (int k = 0; k < 16; ++k) {
      float v = sq[k];
      v += __shfl_xor(v, 1, 64); v += __shfl_xor(v, 2, 64);
      v += __shfl_xor(v, 4, 64); v += __shfl_xor(v, 8, 64);
      sq[k] = v;
    }
    if ((t & 15) == 0) {
      float* xp = xnp + ((size_t)b * 64 + chunk) * 256 + (t >> 4);
#pragma unroll
      for (int k = 0; k < 16; ++k) xp[k * 16] = sq[k];
    }
  }
  __syncthreads();

  // ---- phase 1: per-wave s partial over c-quarter; lane owns n=lane; w via s_load ----
  {
    const int cq = __builtin_amdgcn_readfirstlane(wv);
    float sacc[8];
#pragma unroll
    for (int g = 0; g < 8; ++g) sacc[g] = 0.f;
    const float* wb = wg + (size_t)b * 2048 + cq * 512;  // uniform -> s_load
    const int c0 = cq * 64;
#pragma unroll 8
    for (int cc = 0; cc < 64; ++cc) {
      float xv = xs[(c0 + cc) * STR + lane];
      const float* wc = wb + cc * 8;
#pragma unroll
      for (int g = 0; g < 8; ++g) sacc[g] = fmaf(wc[g], xv, sacc[g]);
    }
#pragma unroll
    for (int g = 0; g < 8; ++g) pool[(cq * 8 + g) * PSTR + lane] = sacc[g];
  }
  __syncthreads();
  // finalize s-tile + spart2 (sumsq over tile n)
#pragma unroll
  for (int k = 0; k < 2; ++k) {
    int g = (t >> 6) + 4 * k;
    int n = t & 63;
    float v = pool[(0 * 8 + g) * PSTR + n] + pool[(1 * 8 + g) * PSTR + n] +
              pool[(2 * 8 + g) * PSTR + n] + pool[(3 * 8 + g) * PSTR + n];
    st[g * STR + n] = v;
    float s2 = v * v;
#pragma unroll
    for (int off = 1; off < 64; off <<= 1) s2 += __shfl_xor(s2, off, 64);
    if (n == 0) spart2[((size_t)b * 64 + chunk) * 8 + g] = s2;
  }
  __syncthreads();

  // ---- phase 2: sim partials. thread: co=t&31 (c=co+32k), nq=t>>5 (8 n each) ----
  const int co = t & 31;
  const int nq = t >> 5;
  float4 sva[8], svb[8];
#pragma unroll
  for (int g = 0; g < 8; ++g) {
    sva[g] = *(const float4*)&st[g * STR + nq * 8];
    svb[g] = *(const float4*)&st[g * STR + nq * 8 + 4];
  }
  float acc[8][8];
#pragma unroll
  for (int k = 0; k < 8; ++k)
#pragma unroll
    for (int g = 0; g < 8; ++g) acc[k][g] = 0.f;
#pragma unroll
  for (int k = 0; k < 8; ++k) {
    const int c = co + 32 * k;
    float4 xa = *(const float4*)&xs[c * STR + nq * 8];
    float4 xb2 = *(const float4*)&xs[c * STR + nq * 8 + 4];
#pragma unroll
    for (int g = 0; g < 8; ++g) {
      float a = acc[k][g];
      a = fmaf(xa.x, sva[g].x, a);
      a = fmaf(xa.y, sva[g].y, a);
      a = fmaf(xa.z, sva[g].z, a);
      a = fmaf(xa.w, sva[g].w, a);
      a = fmaf(xb2.x, svb[g].x, a);
      a = fmaf(xb2.y, svb[g].y, a);
      a = fmaf(xb2.z, svb[g].z, a);
      a = fmaf(xb2.w, svb[g].w, a);
      acc[k][g] = a;
    }
  }
  // combine nq pairs within wave (lanes l <-> l+32 differ only in nq)
#pragma unroll
  for (int k = 0; k < 8; ++k)
#pragma unroll
    for (int g = 0; g < 8; ++g) acc[k][g] += __shfl_xor(acc[k][g], 32, 64);
  __syncthreads();  // done reading xs/st -> reuse xs as pool2[co][(k*4+wv)*8+g], stride 260
  float* pool2 = xs;
  if (lane < 32) {
#pragma unroll
    for (int k = 0; k < 8; ++k) {
      *(float4*)&pool2[co * 260 + (k * 4 + wv) * 8 + 0] =
          make_float4(acc[k][0], acc[k][1], acc[k][2], acc[k][3]);
      *(float4*)&pool2[co * 260 + (k * 4 + wv) * 8 + 4] =
          make_float4(acc[k][4], acc[k][5], acc[k][6], acc[k][7]);
    }
  }
  __syncthreads();
  // merge over waves: output c = t, g = 0..7
  {
    const int mco = t & 31, mk = t >> 5;
    float4 r0 = make_float4(0.f, 0.f, 0.f, 0.f), r1 = r0;
#pragma unroll
    for (int w = 0; w < 4; ++w) {
      float4 a = *(const float4*)&pool2[mco * 260 + (mk * 4 + w) * 8 + 0];
      float4 bq = *(const float4*)&pool2[mco * 260 + (mk * 4 + w) * 8 + 4];
      r0.x += a.x; r0.y += a.y; r0.z += a.z; r0.w += a.w;
      r1.x += bq.x; r1.y += bq.y; r1.z += bq.z; r1.w += bq.w;
    }
    float* sp = simpart + (((size_t)b * 64 + chunk) * 256 + t) * 8;
    *(float4*)sp = r0;
    *(float4*)(sp + 4) = r1;
  }
}

// ---------------- logits += sim/(xn*sn); !FINAL: softmax->wg (+xnorm); FINAL: ->d_out -------
// grid: 16 b x 16 c-slices(16). Parallel k-reduction of simpart/xnp/spart2.
template <int FINAL>
__global__ __launch_bounds__(256) void k_upd(const float* __restrict__ simpart,
                                             const float* __restrict__ xnp,
                                             const float* __restrict__ spart2,
                                             float* __restrict__ logits,
                                             float* __restrict__ xnorm,
                                             float* __restrict__ wg,
                                             float* __restrict__ outw) {
  const int b = blockIdx.x >> 4;
  const int c0 = (blockIdx.x & 15) * 16;
  const int t = threadIdx.x;
  __shared__ float simld[16][8];
  __shared__ float xnl[16];
  __shared__ float snr8[8];
  // sim k-reduction: pair=(cl,g), kh splits k
  {
    const int pair = t >> 1, kh = t & 1;
    const int cl = pair >> 3, g = pair & 7;
    float sm = 0.f;
    const float* sp = simpart + (((size_t)b * 64 + kh * 32) * 256 + c0 + cl) * 8 + g;
#pragma unroll 8
    for (int k = 0; k < 32; ++k) sm += sp[(size_t)k * 2048];
    sm += __shfl_xor(sm, 1, 64);
    if (kh == 0) simld[cl][g] = sm;
  }
  // xnorm
  {
    const int cl2 = t >> 4, kq = t & 15;
    if (!FINAL) {
      float p = 0.f;
#pragma unroll
      for (int j = 0; j < 4; ++j)
        p += xnp[((size_t)b * 64 + kq + 16 * j) * 256 + c0 + cl2];
      p += __shfl_xor(p, 1, 64); p += __shfl_xor(p, 2, 64);
      p += __shfl_xor(p, 4, 64); p += __shfl_xor(p, 8, 64);
      if (kq == 0) {
        float xn = fmaxf(sqrtf(p), EPSF);
        xnl[cl2] = xn;
        xnorm[b * 256 + c0 + cl2] = xn;
      }
    } else {
      if (kq == 0) xnl[cl2] = xnorm[b * 256 + c0 + cl2];
    }
  }
  // s-norms
  if (t < 64) {
    const int g2 = t >> 3, kq = t & 7;
    float p = 0.f;
#pragma unroll
    for (int j = 0; j < 8; ++j) p += spart2[((size_t)b * 64 + kq + 8 * j) * 8 + g2];
    p += __shfl_xor(p, 1, 64); p += __shfl_xor(p, 2, 64); p += __shfl_xor(p, 4, 64);
    if (kq == 0) snr8[g2] = 1.f / fmaxf(sqrtf(p), EPSF);
  }
  __syncthreads();
  if (t < 16) {
    const int c = c0 + t;
    float* lp = logits + ((size_t)b * 256 + c) * 8;
    float4 l0 = *(const float4*)lp, l1 = *(const float4*)(lp + 4);
    float lg[8] = {l0.x, l0.y, l0.z, l0.w, l1.x, l1.y, l1.z, l1.w};
    const float xni = 1.f / xnl[t];
#pragma unroll
    for (int g = 0; g < 8; ++g) lg[g] += simld[t][g] * xni * snr8[g];
    if (!FINAL) {
      *(float4*)lp = make_float4(lg[0], lg[1], lg[2], lg[3]);
      *(float4*)(lp + 4) = make_float4(lg[4], lg[5], lg[6], lg[7]);
    }
    float m = lg[0];
#pragma unroll
    for (int g = 1; g < 8; ++g) m = fmaxf(m, lg[g]);
    float sum = 0.f;
#pragma unroll
    for (int g = 0; g < 8; ++g) { lg[g] = __expf(lg[g] - m); sum += lg[g]; }
    float r = 1.f / sum;
    float* dst = FINAL ? outw : wg;
    float4* op = (float4*)(dst + ((size_t)b * 256 + c) * 8);
    op[0] = make_float4(lg[0] * r, lg[1] * r, lg[2] * r, lg[3] * r);
    op[1] = make_float4(lg[4] * r, lg[5] * r, lg[6] * r, lg[7] * r);
  }
}

extern "C" void kernel_launch(void* const* d_in, const int* in_sizes, int n_in,
                              void* d_out, int out_size, void* d_ws, size_t ws_size,
                              hipStream_t stream) {
  const float* x = (const float*)d_in[0];
  const float* ga = (const float*)d_in[1];
  const float* conv_w = (const float*)d_in[2];
  const float* conv_b = (const float*)d_in[3];
  const float* lin_w = (const float*)d_in[4];
  const float* lin_b = (const float*)d_in[5];
  float* out = (float*)d_out;
  float* outx = out + 32768;  // x passthrough region

  float* ws = (float*)d_ws;
  float* pooledpart = ws;           // 2048
  float* logits = ws + 32768;       // 32768
  float* wg = ws + 65536;           // 32768
  float* xnorm = ws + 98304;        // 4096
  float* xnp = ws + 102400;         // 262144
  float* spart2 = ws + 364544;      // 8192
  float* simpart = ws + 372736;     // 2097152

  k_conv<<<1024, 256, 0, stream>>>(x, conv_w, conv_b, pooledpart);
  k_logits<<<16, 256, 0, stream>>>(pooledpart, lin_w, lin_b, ga, logits, wg);

  // iteration 1 (also writes x passthrough + xnorm partials)
  k_route<1><<<1024, 256, 0, stream>>>(x, wg, outx, xnp, spart2, simpart);
  k_upd<0><<<256, 256, 0, stream>>>(simpart, xnp, spart2, logits, xnorm, wg, out);

  // iteration 2 (+ final softmax into d_out)
  k_route<0><<<1024, 256, 0, stream>>>(x, wg, outx, xnp, spart2, simpart);
  k_upd<1><<<256, 256, 0, stream>>>(simpart, xnp, spart2, logits, xnorm, wg, out);
}

// Round 8
// 147.672 us; speedup vs baseline: 1.0552x; 1.0552x over previous
//
#include <hip/hip_runtime.h>

#define BB 16
#define CC 256
#define NN 4096
#define CN (CC*NN)
#define GG 8
#define EPSF 1e-8f
#define NT 64      // n-tile per block
#define STR 68     // padded LDS row stride (words); 68*4=272 B, 16B-aligned rows
#define PSTR 65    // pool stride (odd -> conflict-free b32)

// ---------------- transpose conv_w -> wT[c][d] ----------------------------------------------
__global__ __launch_bounds__(256) void k_wt(const float* __restrict__ conv_w,
                                            float* __restrict__ wT) {
  int o = blockIdx.x * 256 + threadIdx.x;  // 16384
  int d = o >> 8, c = o & 255;
  wT[c * 64 + d] = conv_w[d * 256 + c];
}

// ---------------- prep pass: x passthrough + xnorm partials + conv/relu/pool partials -------
// grid: 16 b x 64 n-tiles(64). block 256 = 4 waves. LDS x tile [256][STR].
// Conv phase: wave wv owns d in [wv*16, wv*16+16); lane owns n=lane; weights wT via
// wave-uniform s_load (L2-resident); x from LDS (conflict-free row reads).
__global__ __launch_bounds__(256, 2) void k_prep(const float* __restrict__ x,
                                                 const float* __restrict__ wT,
                                                 const float* __restrict__ conv_b,
                                                 float* __restrict__ xout,
                                                 float* __restrict__ xnp,
                                                 float* __restrict__ pooledpart) {
  const int b = blockIdx.x >> 6;
  const int chunk = blockIdx.x & 63;
  const int t = threadIdx.x;
  const int lane = t & 63, wv = t >> 6;
  __shared__ float xs[256 * STR];  // 69632 B

  // stage x tile (+ passthrough write + per-row sumsq partials)
  const float* xb = x + (size_t)b * CN + chunk * NT;
  float sq[16];
#pragma unroll
  for (int k = 0; k < 16; ++k) {
    int f = k * 256 + t;
    int r = f >> 4, j = f & 15;
    float4 v = *(const float4*)(xb + (size_t)r * NN + j * 4);
    *(float4*)&xs[r * STR + j * 4] = v;
    *(float4*)(xout + (size_t)b * CN + (size_t)r * NN + chunk * NT + j * 4) = v;
    sq[k] = v.x * v.x + v.y * v.y + v.z * v.z + v.w * v.w;
  }
#pragma unroll
  for (int k = 0; k < 16; ++k) {
    float v = sq[k];
    v += __shfl_xor(v, 1, 64); v += __shfl_xor(v, 2, 64);
    v += __shfl_xor(v, 4, 64); v += __shfl_xor(v, 8, 64);
    sq[k] = v;
  }
  if ((t & 15) == 0) {
    float* xp = xnp + ((size_t)b * 64 + chunk) * 256 + (t >> 4);
#pragma unroll
    for (int k = 0; k < 16; ++k) xp[k * 16] = sq[k];
  }
  __syncthreads();

  // conv: acc[i] = sum_c wT[c][d0+i] * xs[c][lane]
  const int d0 = __builtin_amdgcn_readfirstlane(wv) * 16;
  float acc[16];
#pragma unroll
  for (int i = 0; i < 16; ++i) acc[i] = 0.f;
#pragma unroll 4
  for (int c = 0; c < 256; ++c) {
    float xv = xs[c * STR + lane];
    const float* wc = wT + c * 64 + d0;  // wave-uniform -> s_load (64B contiguous)
#pragma unroll
    for (int i = 0; i < 16; ++i) acc[i] = fmaf(wc[i], xv, acc[i]);
  }
  const float* cb = conv_b + d0;  // wave-uniform
#pragma unroll
  for (int i = 0; i < 16; ++i) {
    float h = fmaxf(acc[i] + cb[i], 0.f);
#pragma unroll
    for (int off = 1; off < 64; off <<= 1) h += __shfl_xor(h, off, 64);
    acc[i] = h;
  }
  if (lane == 0) {
    float* pp = pooledpart + ((size_t)b * 64 + chunk) * 64 + d0;
#pragma unroll
    for (int i = 0; i < 16; ++i) pp[i] = acc[i];
  }
}

// ---------------- pooled-reduce + logits + log(ga) + softmax -> wg --------------------------
__global__ __launch_bounds__(256) void k_logits(const float* __restrict__ pooledpart,
                                                const float* __restrict__ lin_w,
                                                const float* __restrict__ lin_b,
                                                const float* __restrict__ ga,
                                                float* __restrict__ logits,
                                                float* __restrict__ wg) {
  const int b = blockIdx.x, t = threadIdx.x;
  __shared__ float ps[64];
  if (t < 64) {
    float s = 0.f;
#pragma unroll 8
    for (int k = 0; k < 64; ++k) s += pooledpart[((size_t)b * 64 + k) * 64 + t];
    ps[t] = s * (1.f / 4096.f);
  }
  __syncthreads();
  const int c = t;
  float out[8];
#pragma unroll
  for (int g = 0; g < 8; ++g) {
    const float4* wr = (const float4*)(lin_w + ((size_t)c * 8 + g) * 64);
    float s = 0.f;
#pragma unroll
    for (int k4 = 0; k4 < 16; ++k4) {
      float4 wv = wr[k4];
      s += wv.x * ps[k4 * 4] + wv.y * ps[k4 * 4 + 1] + wv.z * ps[k4 * 4 + 2] +
           wv.w * ps[k4 * 4 + 3];
    }
    out[g] = s + lin_b[c * 8 + g] + logf(ga[((size_t)b * 256 + c) * 8 + g] + EPSF);
  }
  float* lp = logits + ((size_t)b * 256 + c) * 8;
  *(float4*)lp = make_float4(out[0], out[1], out[2], out[3]);
  *(float4*)(lp + 4) = make_float4(out[4], out[5], out[6], out[7]);
  float m = out[0];
#pragma unroll
  for (int g = 1; g < 8; ++g) m = fmaxf(m, out[g]);
  float sum = 0.f;
#pragma unroll
  for (int g = 0; g < 8; ++g) { out[g] = __expf(out[g] - m); sum += out[g]; }
  float r = 1.f / sum;
  float4* op = (float4*)(wg + ((size_t)b * 256 + c) * 8);
  op[0] = make_float4(out[0] * r, out[1] * r, out[2] * r, out[3] * r);
  op[1] = make_float4(out[4] * r, out[5] * r, out[6] * r, out[7] * r);
}

// ---------------- fused routing iteration: s-tile + sim partials (x staged once) ------------
// grid: 16 b x 64 n-tiles(64). block 256. LDS ~80.1KB -> 2 blocks/CU. Pure read pass.
__global__ __launch_bounds__(256, 2) void k_route(const float* __restrict__ x,
                                                  const float* __restrict__ wg,
                                                  float* __restrict__ spart2,
                                                  float* __restrict__ simpart) {
  const int b = blockIdx.x >> 6;
  const int chunk = blockIdx.x & 63;
  const int t = threadIdx.x;
  const int lane = t & 63, wv = t >> 6;
  __shared__ float xs[256 * STR];      // 69632 B (reused as pool2 in merge)
  __shared__ float st[8 * STR];        // 2176 B   s tile
  __shared__ float pool[32 * PSTR];    // 8320 B   phase-1 per-wave partials

  // stage x tile: f = k*256+t -> row r=f>>4 (c), float4-col j=f&15
  const float* xb = x + (size_t)b * CN + chunk * NT;
#pragma unroll
  for (int k = 0; k < 16; ++k) {
    int f = k * 256 + t;
    int r = f >> 4, j = f & 15;
    float4 v = *(const float4*)(xb + (size_t)r * NN + j * 4);
    *(float4*)&xs[r * STR + j * 4] = v;
  }
  __syncthreads();

  // ---- phase 1: per-wave s partial over c-quarter; lane owns n=lane; w via s_load ----
  {
    const int cq = __builtin_amdgcn_readfirstlane(wv);
    float sacc[8];
#pragma unroll
    for (int g = 0; g < 8; ++g) sacc[g] = 0.f;
    const float* wb = wg + (size_t)b * 2048 + cq * 512;  // uniform -> s_load
    const int c0 = cq * 64;
#pragma unroll 8
    for (int cc = 0; cc < 64; ++cc) {
      float xv = xs[(c0 + cc) * STR + lane];
      const float* wc = wb + cc * 8;
#pragma unroll
      for (int g = 0; g < 8; ++g) sacc[g] = fmaf(wc[g], xv, sacc[g]);
    }
#pragma unroll
    for (int g = 0; g < 8; ++g) pool[(cq * 8 + g) * PSTR + lane] = sacc[g];
  }
  __syncthreads();
  // finalize s-tile + spart2 (sumsq over tile n)
#pragma unroll
  for (int k = 0; k < 2; ++k) {
    int g = (t >> 6) + 4 * k;
    int n = t & 63;
    float v = pool[(0 * 8 + g) * PSTR + n] + pool[(1 * 8 + g) * PSTR + n] +
              pool[(2 * 8 + g) * PSTR + n] + pool[(3 * 8 + g) * PSTR + n];
    st[g * STR + n] = v;
    float s2 = v * v;
#pragma unroll
    for (int off = 1; off < 64; off <<= 1) s2 += __shfl_xor(s2, off, 64);
    if (n == 0) spart2[((size_t)b * 64 + chunk) * 8 + g] = s2;
  }
  __syncthreads();

  // ---- phase 2: sim partials. thread: co=t&31 (c=co+32k), nq=t>>5 (8 n each) ----
  const int co = t & 31;
  const int nq = t >> 5;
  float4 sva[8], svb[8];
#pragma unroll
  for (int g = 0; g < 8; ++g) {
    sva[g] = *(const float4*)&st[g * STR + nq * 8];
    svb[g] = *(const float4*)&st[g * STR + nq * 8 + 4];
  }
  float acc[8][8];
#pragma unroll
  for (int k = 0; k < 8; ++k)
#pragma unroll
    for (int g = 0; g < 8; ++g) acc[k][g] = 0.f;
#pragma unroll
  for (int k = 0; k < 8; ++k) {
    const int c = co + 32 * k;
    float4 xa = *(const float4*)&xs[c * STR + nq * 8];
    float4 xb2 = *(const float4*)&xs[c * STR + nq * 8 + 4];
#pragma unroll
    for (int g = 0; g < 8; ++g) {
      float a = acc[k][g];
      a = fmaf(xa.x, sva[g].x, a);
      a = fmaf(xa.y, sva[g].y, a);
      a = fmaf(xa.z, sva[g].z, a);
      a = fmaf(xa.w, sva[g].w, a);
      a = fmaf(xb2.x, svb[g].x, a);
      a = fmaf(xb2.y, svb[g].y, a);
      a = fmaf(xb2.z, svb[g].z, a);
      a = fmaf(xb2.w, svb[g].w, a);
      acc[k][g] = a;
    }
  }
  // combine nq pairs within wave (lanes l <-> l+32 differ only in nq)
#pragma unroll
  for (int k = 0; k < 8; ++k)
#pragma unroll
    for (int g = 0; g < 8; ++g) acc[k][g] += __shfl_xor(acc[k][g], 32, 64);
  __syncthreads();  // done reading xs/st -> reuse xs as pool2[co][(k*4+wv)*8+g], stride 260
  float* pool2 = xs;
  if (lane < 32) {
#pragma unroll
    for (int k = 0; k < 8; ++k) {
      *(float4*)&pool2[co * 260 + (k * 4 + wv) * 8 + 0] =
          make_float4(acc[k][0], acc[k][1], acc[k][2], acc[k][3]);
      *(float4*)&pool2[co * 260 + (k * 4 + wv) * 8 + 4] =
          make_float4(acc[k][4], acc[k][5], acc[k][6], acc[k][7]);
    }
  }
  __syncthreads();
  // merge over waves: output c = t, g = 0..7
  {
    const int mco = t & 31, mk = t >> 5;
    float4 r0 = make_float4(0.f, 0.f, 0.f, 0.f), r1 = r0;
#pragma unroll
    for (int w = 0; w < 4; ++w) {
      float4 a = *(const float4*)&pool2[mco * 260 + (mk * 4 + w) * 8 + 0];
      float4 bq = *(const float4*)&pool2[mco * 260 + (mk * 4 + w) * 8 + 4];
      r0.x += a.x; r0.y += a.y; r0.z += a.z; r0.w += a.w;
      r1.x += bq.x; r1.y += bq.y; r1.z += bq.z; r1.w += bq.w;
    }
    float* sp = simpart + (((size_t)b * 64 + chunk) * 256 + t) * 8;
    *(float4*)sp = r0;
    *(float4*)(sp + 4) = r1;
  }
}

// ---------------- logits += sim/(xn*sn); !FINAL: softmax->wg (+xnorm); FINAL: ->d_out -------
// grid: 16 b x 16 c-slices(16). Parallel k-reduction of simpart/xnp/spart2.
template <int FINAL>
__global__ __launch_bounds__(256) void k_upd(const float* __restrict__ simpart,
                                             const float* __restrict__ xnp,
                                             const float* __restrict__ spart2,
                                             float* __restrict__ logits,
                                             float* __restrict__ xnorm,
                                             float* __restrict__ wg,
                                             float* __restrict__ outw) {
  const int b = blockIdx.x >> 4;
  const int c0 = (blockIdx.x & 15) * 16;
  const int t = threadIdx.x;
  __shared__ float simld[16][8];
  __shared__ float xnl[16];
  __shared__ float snr8[8];
  // sim k-reduction: pair=(cl,g), kh splits k
  {
    const int pair = t >> 1, kh = t & 1;
    const int cl = pair >> 3, g = pair & 7;
    float sm = 0.f;
    const float* sp = simpart + (((size_t)b * 64 + kh * 32) * 256 + c0 + cl) * 8 + g;
#pragma unroll 8
    for (int k = 0; k < 32; ++k) sm += sp[(size_t)k * 2048];
    sm += __shfl_xor(sm, 1, 64);
    if (kh == 0) simld[cl][g] = sm;
  }
  // xnorm
  {
    const int cl2 = t >> 4, kq = t & 15;
    if (!FINAL) {
      float p = 0.f;
#pragma unroll
      for (int j = 0; j < 4; ++j)
        p += xnp[((size_t)b * 64 + kq + 16 * j) * 256 + c0 + cl2];
      p += __shfl_xor(p, 1, 64); p += __shfl_xor(p, 2, 64);
      p += __shfl_xor(p, 4, 64); p += __shfl_xor(p, 8, 64);
      if (kq == 0) {
        float xn = fmaxf(sqrtf(p), EPSF);
        xnl[cl2] = xn;
        xnorm[b * 256 + c0 + cl2] = xn;
      }
    } else {
      if (kq == 0) xnl[cl2] = xnorm[b * 256 + c0 + cl2];
    }
  }
  // s-norms
  if (t < 64) {
    const int g2 = t >> 3, kq = t & 7;
    float p = 0.f;
#pragma unroll
    for (int j = 0; j < 8; ++j) p += spart2[((size_t)b * 64 + kq + 8 * j) * 8 + g2];
    p += __shfl_xor(p, 1, 64); p += __shfl_xor(p, 2, 64); p += __shfl_xor(p, 4, 64);
    if (kq == 0) snr8[g2] = 1.f / fmaxf(sqrtf(p), EPSF);
  }
  __syncthreads();
  if (t < 16) {
    const int c = c0 + t;
    float* lp = logits + ((size_t)b * 256 + c) * 8;
    float4 l0 = *(const float4*)lp, l1 = *(const float4*)(lp + 4);
    float lg[8] = {l0.x, l0.y, l0.z, l0.w, l1.x, l1.y, l1.z, l1.w};
    const float xni = 1.f / xnl[t];
#pragma unroll
    for (int g = 0; g < 8; ++g) lg[g] += simld[t][g] * xni * snr8[g];
    if (!FINAL) {
      *(float4*)lp = make_float4(lg[0], lg[1], lg[2], lg[3]);
      *(float4*)(lp + 4) = make_float4(lg[4], lg[5], lg[6], lg[7]);
    }
    float m = lg[0];
#pragma unroll
    for (int g = 1; g < 8; ++g) m = fmaxf(m, lg[g]);
    float sum = 0.f;
#pragma unroll
    for (int g = 0; g < 8; ++g) { lg[g] = __expf(lg[g] - m); sum += lg[g]; }
    float r = 1.f / sum;
    float* dst = FINAL ? outw : wg;
    float4* op = (float4*)(dst + ((size_t)b * 256 + c) * 8);
    op[0] = make_float4(lg[0] * r, lg[1] * r, lg[2] * r, lg[3] * r);
    op[1] = make_float4(lg[4] * r, lg[5] * r, lg[6] * r, lg[7] * r);
  }
}

extern "C" void kernel_launch(void* const* d_in, const int* in_sizes, int n_in,
                              void* d_out, int out_size, void* d_ws, size_t ws_size,
                              hipStream_t stream) {
  const float* x = (const float*)d_in[0];
  const float* ga = (const float*)d_in[1];
  const float* conv_w = (const float*)d_in[2];
  const float* conv_b = (const float*)d_in[3];
  const float* lin_w = (const float*)d_in[4];
  const float* lin_b = (const float*)d_in[5];
  float* out = (float*)d_out;
  float* outx = out + 32768;  // x passthrough region

  float* ws = (float*)d_ws;
  float* pooledpart = ws;           // 65536
  float* wT = ws + 65536;           // 16384
  float* logits = ws + 81920;       // 32768
  float* wg = ws + 114688;          // 32768
  float* xnorm = ws + 147456;       // 4096
  float* xnp = ws + 151552;         // 262144
  float* spart2 = ws + 413696;      // 8192
  float* simpart = ws + 421888;     // 2097152

  k_wt<<<64, 256, 0, stream>>>(conv_w, wT);
  // prep: x passthrough + xnorm partials + conv/relu/pool partials (one x stream)
  k_prep<<<1024, 256, 0, stream>>>(x, wT, conv_b, outx, xnp, pooledpart);
  k_logits<<<16, 256, 0, stream>>>(pooledpart, lin_w, lin_b, ga, logits, wg);

  // iteration 1
  k_route<<<1024, 256, 0, stream>>>(x, wg, spart2, simpart);
  k_upd<0><<<256, 256, 0, stream>>>(simpart, xnp, spart2, logits, xnorm, wg, out);

  // iteration 2 (+ final softmax into d_out)
  k_route<<<1024, 256, 0, stream>>>(x, wg, spart2, simpart);
  k_upd<1><<<256, 256, 0, stream>>>(simpart, xnp, spart2, logits, xnorm, wg, out);
}

// Round 9
// 141.896 us; speedup vs baseline: 1.0982x; 1.0407x over previous
//
#include <hip/hip_runtime.h>

#define BB 16
#define CC 256
#define NN 4096
#define CN (CC*NN)
#define GG 8
#define EPSF 1e-8f
#define NT 64      // n-tile per block
#define STR 68     // padded LDS row stride (words); 68*4=272 B, 16B-aligned rows
#define PSTR 65    // pool stride (odd -> conflict-free b32)

// ---------------- transpose conv_w -> wT[c][d] ----------------------------------------------
__global__ __launch_bounds__(256) void k_wt(const float* __restrict__ conv_w,
                                            float* __restrict__ wT) {
  int o = blockIdx.x * 256 + threadIdx.x;  // 16384
  int d = o >> 8, c = o & 255;
  wT[c * 64 + d] = conv_w[d * 256 + c];
}

// ---------------- prep pass: x passthrough + xnorm partials + conv/relu/pool partials -------
// grid: 16 b x 64 n-tiles(64). block 512 = 8 waves -> 16 waves/CU (4/SIMD) at 2 blocks/CU.
// Staging: 8 loads first, LDS+sq from regs, stores LAST (don't stall load pipeline).
// Conv: wave wv owns d in [wv*8, wv*8+8); lane owns n; weights via wave-uniform s_load.
__global__ __launch_bounds__(512) void k_prep(const float* __restrict__ x,
                                              const float* __restrict__ wT,
                                              const float* __restrict__ conv_b,
                                              float* __restrict__ xout,
                                              float* __restrict__ xnp,
                                              float* __restrict__ pooledpart) {
  const int b = blockIdx.x >> 6;
  const int chunk = blockIdx.x & 63;
  const int t = threadIdx.x;
  const int lane = t & 63, wv = t >> 6;  // wv 0..7
  __shared__ float xs[256 * STR];  // 69632 B

  // stage x tile: f = k*512+t -> row r = k*32 + (t>>4), float4-col j = t&15
  const float* xb = x + (size_t)b * CN + chunk * NT;
  const int r0 = t >> 4, j = t & 15;
  float4 v[8];
  float sq[8];
#pragma unroll
  for (int k = 0; k < 8; ++k)
    v[k] = *(const float4*)(xb + (size_t)(k * 32 + r0) * NN + j * 4);
#pragma unroll
  for (int k = 0; k < 8; ++k) {
    *(float4*)&xs[(k * 32 + r0) * STR + j * 4] = v[k];
    sq[k] = v[k].x * v[k].x + v[k].y * v[k].y + v[k].z * v[k].z + v[k].w * v[k].w;
  }
  float* xo = xout + (size_t)b * CN + chunk * NT;
#pragma unroll
  for (int k = 0; k < 8; ++k)
    *(float4*)(xo + (size_t)(k * 32 + r0) * NN + j * 4) = v[k];
  // per-row sumsq: 16 lanes share a row
#pragma unroll
  for (int k = 0; k < 8; ++k) {
    float s = sq[k];
    s += __shfl_xor(s, 1, 64); s += __shfl_xor(s, 2, 64);
    s += __shfl_xor(s, 4, 64); s += __shfl_xor(s, 8, 64);
    sq[k] = s;
  }
  if ((t & 15) == 0) {
    float* xp = xnp + ((size_t)b * 64 + chunk) * 256 + r0;
#pragma unroll
    for (int k = 0; k < 8; ++k) xp[k * 32] = sq[k];
  }
  __syncthreads();

  // conv: acc[i] = sum_c wT[c][d0+i] * xs[c][lane], d0 = wv*8
  const int d0 = __builtin_amdgcn_readfirstlane(wv) * 8;
  float acc[8];
#pragma unroll
  for (int i = 0; i < 8; ++i) acc[i] = 0.f;
#pragma unroll 4
  for (int c = 0; c < 256; ++c) {
    float xv = xs[c * STR + lane];
    const float* wc = wT + c * 64 + d0;  // wave-uniform -> s_load (32B)
#pragma unroll
    for (int i = 0; i < 8; ++i) acc[i] = fmaf(wc[i], xv, acc[i]);
  }
  const float* cb = conv_b + d0;  // wave-uniform
#pragma unroll
  for (int i = 0; i < 8; ++i) {
    float h = fmaxf(acc[i] + cb[i], 0.f);
#pragma unroll
    for (int off = 1; off < 64; off <<= 1) h += __shfl_xor(h, off, 64);
    acc[i] = h;
  }
  if (lane == 0) {
    float* pp = pooledpart + ((size_t)b * 64 + chunk) * 64 + d0;
#pragma unroll
    for (int i = 0; i < 8; ++i) pp[i] = acc[i];
  }
}

// ---------------- pooled-reduce + logits + log(ga) + softmax -> wg --------------------------
__global__ __launch_bounds__(256) void k_logits(const float* __restrict__ pooledpart,
                                                const float* __restrict__ lin_w,
                                                const float* __restrict__ lin_b,
                                                const float* __restrict__ ga,
                                                float* __restrict__ logits,
                                                float* __restrict__ wg) {
  const int b = blockIdx.x, t = threadIdx.x;
  __shared__ float ps[64];
  if (t < 64) {
    float s = 0.f;
#pragma unroll 8
    for (int k = 0; k < 64; ++k) s += pooledpart[((size_t)b * 64 + k) * 64 + t];
    ps[t] = s * (1.f / 4096.f);
  }
  __syncthreads();
  const int c = t;
  float out[8];
#pragma unroll
  for (int g = 0; g < 8; ++g) {
    const float4* wr = (const float4*)(lin_w + ((size_t)c * 8 + g) * 64);
    float s = 0.f;
#pragma unroll
    for (int k4 = 0; k4 < 16; ++k4) {
      float4 wv = wr[k4];
      s += wv.x * ps[k4 * 4] + wv.y * ps[k4 * 4 + 1] + wv.z * ps[k4 * 4 + 2] +
           wv.w * ps[k4 * 4 + 3];
    }
    out[g] = s + lin_b[c * 8 + g] + logf(ga[((size_t)b * 256 + c) * 8 + g] + EPSF);
  }
  float* lp = logits + ((size_t)b * 256 + c) * 8;
  *(float4*)lp = make_float4(out[0], out[1], out[2], out[3]);
  *(float4*)(lp + 4) = make_float4(out[4], out[5], out[6], out[7]);
  float m = out[0];
#pragma unroll
  for (int g = 1; g < 8; ++g) m = fmaxf(m, out[g]);
  float sum = 0.f;
#pragma unroll
  for (int g = 0; g < 8; ++g) { out[g] = __expf(out[g] - m); sum += out[g]; }
  float r = 1.f / sum;
  float4* op = (float4*)(wg + ((size_t)b * 256 + c) * 8);
  op[0] = make_float4(out[0] * r, out[1] * r, out[2] * r, out[3] * r);
  op[1] = make_float4(out[4] * r, out[5] * r, out[6] * r, out[7] * r);
}

// ---------------- fused routing iteration: s-tile + sim partials (x staged once) ------------
// grid: 16 b x 64 n-tiles(64). block 256. LDS ~80.1KB -> 2 blocks/CU. Pure read pass.
__global__ __launch_bounds__(256, 2) void k_route(const float* __restrict__ x,
                                                  const float* __restrict__ wg,
                                                  float* __restrict__ spart2,
                                                  float* __restrict__ simpart) {
  const int b = blockIdx.x >> 6;
  const int chunk = blockIdx.x & 63;
  const int t = threadIdx.x;
  const int lane = t & 63, wv = t >> 6;
  __shared__ float xs[256 * STR];      // 69632 B (reused as pool2 in merge)
  __shared__ float st[8 * STR];        // 2176 B   s tile
  __shared__ float pool[32 * PSTR];    // 8320 B   phase-1 per-wave partials

  // stage x tile: f = k*256+t -> row r=f>>4 (c), float4-col j=f&15
  const float* xb = x + (size_t)b * CN + chunk * NT;
#pragma unroll
  for (int k = 0; k < 16; ++k) {
    int f = k * 256 + t;
    int r = f >> 4, j = f & 15;
    float4 v = *(const float4*)(xb + (size_t)r * NN + j * 4);
    *(float4*)&xs[r * STR + j * 4] = v;
  }
  __syncthreads();

  // ---- phase 1: per-wave s partial over c-quarter; lane owns n=lane; w via s_load ----
  {
    const int cq = __builtin_amdgcn_readfirstlane(wv);
    float sacc[8];
#pragma unroll
    for (int g = 0; g < 8; ++g) sacc[g] = 0.f;
    const float* wb = wg + (size_t)b * 2048 + cq * 512;  // uniform -> s_load
    const int c0 = cq * 64;
#pragma unroll 8
    for (int cc = 0; cc < 64; ++cc) {
      float xv = xs[(c0 + cc) * STR + lane];
      const float* wc = wb + cc * 8;
#pragma unroll
      for (int g = 0; g < 8; ++g) sacc[g] = fmaf(wc[g], xv, sacc[g]);
    }
#pragma unroll
    for (int g = 0; g < 8; ++g) pool[(cq * 8 + g) * PSTR + lane] = sacc[g];
  }
  __syncthreads();
  // finalize s-tile + spart2 (sumsq over tile n)
#pragma unroll
  for (int k = 0; k < 2; ++k) {
    int g = (t >> 6) + 4 * k;
    int n = t & 63;
    float v = pool[(0 * 8 + g) * PSTR + n] + pool[(1 * 8 + g) * PSTR + n] +
              pool[(2 * 8 + g) * PSTR + n] + pool[(3 * 8 + g) * PSTR + n];
    st[g * STR + n] = v;
    float s2 = v * v;
#pragma unroll
    for (int off = 1; off < 64; off <<= 1) s2 += __shfl_xor(s2, off, 64);
    if (n == 0) spart2[((size_t)b * 64 + chunk) * 8 + g] = s2;
  }
  __syncthreads();

  // ---- phase 2: sim partials. thread: co=t&31 (c=co+32k), nq=t>>5 (8 n each) ----
  const int co = t & 31;
  const int nq = t >> 5;
  float4 sva[8], svb[8];
#pragma unroll
  for (int g = 0; g < 8; ++g) {
    sva[g] = *(const float4*)&st[g * STR + nq * 8];
    svb[g] = *(const float4*)&st[g * STR + nq * 8 + 4];
  }
  float acc[8][8];
#pragma unroll
  for (int k = 0; k < 8; ++k)
#pragma unroll
    for (int g = 0; g < 8; ++g) acc[k][g] = 0.f;
#pragma unroll
  for (int k = 0; k < 8; ++k) {
    const int c = co + 32 * k;
    float4 xa = *(const float4*)&xs[c * STR + nq * 8];
    float4 xb2 = *(const float4*)&xs[c * STR + nq * 8 + 4];
#pragma unroll
    for (int g = 0; g < 8; ++g) {
      float a = acc[k][g];
      a = fmaf(xa.x, sva[g].x, a);
      a = fmaf(xa.y, sva[g].y, a);
      a = fmaf(xa.z, sva[g].z, a);
      a = fmaf(xa.w, sva[g].w, a);
      a = fmaf(xb2.x, svb[g].x, a);
      a = fmaf(xb2.y, svb[g].y, a);
      a = fmaf(xb2.z, svb[g].z, a);
      a = fmaf(xb2.w, svb[g].w, a);
      acc[k][g] = a;
    }
  }
  // combine nq pairs within wave (lanes l <-> l+32 differ only in nq)
#pragma unroll
  for (int k = 0; k < 8; ++k)
#pragma unroll
    for (int g = 0; g < 8; ++g) acc[k][g] += __shfl_xor(acc[k][g], 32, 64);
  __syncthreads();  // done reading xs/st -> reuse xs as pool2[co][(k*4+wv)*8+g], stride 260
  float* pool2 = xs;
  if (lane < 32) {
#pragma unroll
    for (int k = 0; k < 8; ++k) {
      *(float4*)&pool2[co * 260 + (k * 4 + wv) * 8 + 0] =
          make_float4(acc[k][0], acc[k][1], acc[k][2], acc[k][3]);
      *(float4*)&pool2[co * 260 + (k * 4 + wv) * 8 + 4] =
          make_float4(acc[k][4], acc[k][5], acc[k][6], acc[k][7]);
    }
  }
  __syncthreads();
  // merge over waves: output c = t, g = 0..7
  {
    const int mco = t & 31, mk = t >> 5;
    float4 r0 = make_float4(0.f, 0.f, 0.f, 0.f), r1 = r0;
#pragma unroll
    for (int w = 0; w < 4; ++w) {
      float4 a = *(const float4*)&pool2[mco * 260 + (mk * 4 + w) * 8 + 0];
      float4 bq = *(const float4*)&pool2[mco * 260 + (mk * 4 + w) * 8 + 4];
      r0.x += a.x; r0.y += a.y; r0.z += a.z; r0.w += a.w;
      r1.x += bq.x; r1.y += bq.y; r1.z += bq.z; r1.w += bq.w;
    }
    float* sp = simpart + (((size_t)b * 64 + chunk) * 256 + t) * 8;
    *(float4*)sp = r0;
    *(float4*)(sp + 4) = r1;
  }
}

// ---------------- logits += sim/(xn*sn); !FINAL: softmax->wg (+xnorm); FINAL: ->d_out -------
// grid: 16 b x 16 c-slices(16). Parallel k-reduction of simpart/xnp/spart2.
template <int FINAL>
__global__ __launch_bounds__(256) void k_upd(const float* __restrict__ simpart,
                                             const float* __restrict__ xnp,
                                             const float* __restrict__ spart2,
                                             float* __restrict__ logits,
                                             float* __restrict__ xnorm,
                                             float* __restrict__ wg,
                                             float* __restrict__ outw) {
  const int b = blockIdx.x >> 4;
  const int c0 = (blockIdx.x & 15) * 16;
  const int t = threadIdx.x;
  __shared__ float simld[16][8];
  __shared__ float xnl[16];
  __shared__ float snr8[8];
  // sim k-reduction: pair=(cl,g), kh splits k
  {
    const int pair = t >> 1, kh = t & 1;
    const int cl = pair >> 3, g = pair & 7;
    float sm = 0.f;
    const float* sp = simpart + (((size_t)b * 64 + kh * 32) * 256 + c0 + cl) * 8 + g;
#pragma unroll 8
    for (int k = 0; k < 32; ++k) sm += sp[(size_t)k * 2048];
    sm += __shfl_xor(sm, 1, 64);
    if (kh == 0) simld[cl][g] = sm;
  }
  // xnorm
  {
    const int cl2 = t >> 4, kq = t & 15;
    if (!FINAL) {
      float p = 0.f;
#pragma unroll
      for (int j = 0; j < 4; ++j)
        p += xnp[((size_t)b * 64 + kq + 16 * j) * 256 + c0 + cl2];
      p += __shfl_xor(p, 1, 64); p += __shfl_xor(p, 2, 64);
      p += __shfl_xor(p, 4, 64); p += __shfl_xor(p, 8, 64);
      if (kq == 0) {
        float xn = fmaxf(sqrtf(p), EPSF);
        xnl[cl2] = xn;
        xnorm[b * 256 + c0 + cl2] = xn;
      }
    } else {
      if (kq == 0) xnl[cl2] = xnorm[b * 256 + c0 + cl2];
    }
  }
  // s-norms
  if (t < 64) {
    const int g2 = t >> 3, kq = t & 7;
    float p = 0.f;
#pragma unroll
    for (int j = 0; j < 8; ++j) p += spart2[((size_t)b * 64 + kq + 8 * j) * 8 + g2];
    p += __shfl_xor(p, 1, 64); p += __shfl_xor(p, 2, 64); p += __shfl_xor(p, 4, 64);
    if (kq == 0) snr8[g2] = 1.f / fmaxf(sqrtf(p), EPSF);
  }
  __syncthreads();
  if (t < 16) {
    const int c = c0 + t;
    float* lp = logits + ((size_t)b * 256 + c) * 8;
    float4 l0 = *(const float4*)lp, l1 = *(const float4*)(lp + 4);
    float lg[8] = {l0.x, l0.y, l0.z, l0.w, l1.x, l1.y, l1.z, l1.w};
    const float xni = 1.f / xnl[t];
#pragma unroll
    for (int g = 0; g < 8; ++g) lg[g] += simld[t][g] * xni * snr8[g];
    if (!FINAL) {
      *(float4*)lp = make_float4(lg[0], lg[1], lg[2], lg[3]);
      *(float4*)(lp + 4) = make_float4(lg[4], lg[5], lg[6], lg[7]);
    }
    float m = lg[0];
#pragma unroll
    for (int g = 1; g < 8; ++g) m = fmaxf(m, lg[g]);
    float sum = 0.f;
#pragma unroll
    for (int g = 0; g < 8; ++g) { lg[g] = __expf(lg[g] - m); sum += lg[g]; }
    float r = 1.f / sum;
    float* dst = FINAL ? outw : wg;
    float4* op = (float4*)(dst + ((size_t)b * 256 + c) * 8);
    op[0] = make_float4(lg[0] * r, lg[1] * r, lg[2] * r, lg[3] * r);
    op[1] = make_float4(lg[4] * r, lg[5] * r, lg[6] * r, lg[7] * r);
  }
}

extern "C" void kernel_launch(void* const* d_in, const int* in_sizes, int n_in,
                              void* d_out, int out_size, void* d_ws, size_t ws_size,
                              hipStream_t stream) {
  const float* x = (const float*)d_in[0];
  const float* ga = (const float*)d_in[1];
  const float* conv_w = (const float*)d_in[2];
  const float* conv_b = (const float*)d_in[3];
  const float* lin_w = (const float*)d_in[4];
  const float* lin_b = (const float*)d_in[5];
  float* out = (float*)d_out;
  float* outx = out + 32768;  // x passthrough region

  float* ws = (float*)d_ws;
  float* pooledpart = ws;           // 65536
  float* wT = ws + 65536;           // 16384
  float* logits = ws + 81920;       // 32768
  float* wg = ws + 114688;          // 32768
  float* xnorm = ws + 147456;       // 4096
  float* xnp = ws + 151552;         // 262144
  float* spart2 = ws + 413696;      // 8192
  float* simpart = ws + 421888;     // 2097152

  k_wt<<<64, 256, 0, stream>>>(conv_w, wT);
  // prep: x passthrough + xnorm partials + conv/relu/pool partials (one x stream)
  k_prep<<<1024, 512, 0, stream>>>(x, wT, conv_b, outx, xnp, pooledpart);
  k_logits<<<16, 256, 0, stream>>>(pooledpart, lin_w, lin_b, ga, logits, wg);

  // iteration 1
  k_route<<<1024, 256, 0, stream>>>(x, wg, spart2, simpart);
  k_upd<0><<<256, 256, 0, stream>>>(simpart, xnp, spart2, logits, xnorm, wg, out);

  // iteration 2 (+ final softmax into d_out)
  k_route<<<1024, 256, 0, stream>>>(x, wg, spart2, simpart);
  k_upd<1><<<256, 256, 0, stream>>>(simpart, xnp, spart2, logits, xnorm, wg, out);
}